// Round 1
// baseline (12869.998 us; speedup 1.0000x reference)
//
#include <hip/hip_runtime.h>
#include <hip/hip_bf16.h>

#define NN     100000
#define SEQ    12
#define WSTR   36   // padded LDS row stride (floats): 144 B, 16B-aligned, banks 4s apart

__device__ __forceinline__ float rcp_fast(float v) { return __builtin_amdgcn_rcpf(v); }
__device__ __forceinline__ float sigm(float v) { return rcp_fast(1.0f + __expf(-v)); }
__device__ __forceinline__ float tanh_fast(float v) {
    return fmaf(-2.0f, rcp_fast(1.0f + __expf(2.0f * v)), 1.0f);
}

// Accumulate 4 gate-row dot products (i,f,g,o) over a 32-vector h.
// Rows for (q, sublane s) are stored at permuted LDS rows rowbase + {0,8,16,24} + s.
__device__ __forceinline__ void dot4x32(const float* w, int rowbase, int s,
                                        const float (&h)[32],
                                        float& ai, float& af, float& ag, float& ao)
{
    const float4* pi = (const float4*)(w + (rowbase +  0 + s) * WSTR);
    const float4* pf = (const float4*)(w + (rowbase +  8 + s) * WSTR);
    const float4* pg = (const float4*)(w + (rowbase + 16 + s) * WSTR);
    const float4* po = (const float4*)(w + (rowbase + 24 + s) * WSTR);
#pragma unroll
    for (int j4 = 0; j4 < 8; ++j4) {
        float4 wa = pi[j4], wb = pf[j4], wc = pg[j4], wd = po[j4];
        ai = fmaf(wa.x, h[4*j4+0], ai); ai = fmaf(wa.y, h[4*j4+1], ai);
        ai = fmaf(wa.z, h[4*j4+2], ai); ai = fmaf(wa.w, h[4*j4+3], ai);
        af = fmaf(wb.x, h[4*j4+0], af); af = fmaf(wb.y, h[4*j4+1], af);
        af = fmaf(wb.z, h[4*j4+2], af); af = fmaf(wb.w, h[4*j4+3], af);
        ag = fmaf(wc.x, h[4*j4+0], ag); ag = fmaf(wc.y, h[4*j4+1], ag);
        ag = fmaf(wc.z, h[4*j4+2], ag); ag = fmaf(wc.w, h[4*j4+3], ag);
        ao = fmaf(wd.x, h[4*j4+0], ao); ao = fmaf(wd.y, h[4*j4+1], ao);
        ao = fmaf(wd.z, h[4*j4+2], ao); ao = fmaf(wd.w, h[4*j4+3], ao);
    }
}

// 8 lanes per node; sublane s owns hidden units k = 4s+q, q in [0,4).
// Weight row r = 32*T + k  ->  permuted LDS row rho(r) = (r&3)*32 + (r>>2) = q*32 + 8T + s.
__global__ __launch_bounds__(512)
void lstm_fused(const float* __restrict__ x,
                const float* __restrict__ Wtp,  const float* __restrict__ btp,
                const float* __restrict__ Wih0, const float* __restrict__ Whh0,
                const float* __restrict__ bih0, const float* __restrict__ bhh0,
                const float* __restrict__ Wih1, const float* __restrict__ Whh1,
                const float* __restrict__ bih1, const float* __restrict__ bhh1,
                const float* __restrict__ Wfc1, const float* __restrict__ bfc1,
                const float* __restrict__ Wfc2, const float* __restrict__ bfc2,
                float* __restrict__ out)
{
    __shared__ __align__(16) float sWhh0[128 * WSTR];
    __shared__ __align__(16) float sWih1[128 * WSTR];
    __shared__ __align__(16) float sWhh1[128 * WSTR];
    __shared__ __align__(16) float sU4[128];   // [k*4 + T]: folded layer0 input weight
    __shared__ __align__(16) float sV4[128];   // [k*4 + T]: folded layer0 bias
    __shared__ __align__(16) float sB14[128];  // [k*4 + T]: bih1 + bhh1
    __shared__ __align__(16) float sFc1[512];  // W_fc1 [32][16] row-major
    __shared__ float sBfc1[16], sWfc2[16], sBfc2;

    const int tid = threadIdx.x;

    // ---- stage weights into LDS (permuted rows, padded stride) ----
#pragma unroll
    for (int it = 0; it < 8; ++it) {
        int i = tid + it * 512;
        int r = i >> 5, j = i & 31;
        int rho = (r & 3) * 32 + (r >> 2);
        sWhh0[rho * WSTR + j] = Whh0[i];
        sWih1[rho * WSTR + j] = Wih1[i];
        sWhh1[rho * WSTR + j] = Whh1[i];
    }
    if (tid < 128) {
        // fold temporal_proj into layer-0 input projection:
        // pre0[row] = x_t * u[row] + v[row]
        float uu = 0.f, vv = 0.f;
#pragma unroll
        for (int d = 0; d < 16; ++d) {
            float w = Wih0[tid * 16 + d];
            uu = fmaf(w, Wtp[d], uu);
            vv = fmaf(w, btp[d], vv);
        }
        int k = tid & 31, T = tid >> 5;
        sU4[k * 4 + T]  = uu;
        sV4[k * 4 + T]  = vv + bih0[tid] + bhh0[tid];
        sB14[k * 4 + T] = bih1[tid] + bhh1[tid];
    }
    sFc1[tid] = Wfc1[tid];  // exactly 512 elements
    if (tid < 16) { sBfc1[tid] = bfc1[tid]; sWfc2[tid] = Wfc2[tid]; }
    if (tid == 0) sBfc2 = bfc2[0];
    __syncthreads();

    const int s    = tid & 7;
    const int node = blockIdx.x * 64 + (tid >> 3);
    if (node >= NN) return;   // whole waves only (64 thr = 8 nodes, boundary aligned)

    const int lane = tid & 63;
    int sel[8];
#pragma unroll
    for (int b = 0; b < 8; ++b) sel[b] = ((lane & ~7) + b) << 2;

    float h0[32], h1[32], c0[4], c1[4], hn[4];
#pragma unroll
    for (int j = 0; j < 32; ++j) { h0[j] = 0.f; h1[j] = 0.f; }
#pragma unroll
    for (int q = 0; q < 4; ++q) { c0[q] = 0.f; c1[q] = 0.f; }

    const float* xp = x + node * 32 + 20;   // last 12 features

#pragma unroll 1
    for (int t = 0; t < SEQ; ++t) {
        float xt = xp[t];

        // ---------- layer 0 ----------
#pragma unroll
        for (int q = 0; q < 4; ++q) {
            int k = 4 * s + q;
            float4 u = *(const float4*)(sU4 + 4 * k);
            float4 v = *(const float4*)(sV4 + 4 * k);
            float ai = fmaf(xt, u.x, v.x);
            float af = fmaf(xt, u.y, v.y);
            float ag = fmaf(xt, u.z, v.z);
            float ao = fmaf(xt, u.w, v.w);
            dot4x32(sWhh0, q * 32, s, h0, ai, af, ag, ao);
            float gi = sigm(ai), gf = sigm(af);
            float gg = tanh_fast(ag), go = sigm(ao);
            float cc = fmaf(gf, c0[q], gi * gg);
            c0[q] = cc;
            hn[q] = go * tanh_fast(cc);
        }
        // replicate new h0 to all 8 lanes of the node
#pragma unroll
        for (int b = 0; b < 8; ++b)
#pragma unroll
            for (int q = 0; q < 4; ++q)
                h0[4 * b + q] = __int_as_float(
                    __builtin_amdgcn_ds_bpermute(sel[b], __float_as_int(hn[q])));

        // ---------- layer 1 ----------
#pragma unroll
        for (int q = 0; q < 4; ++q) {
            int k = 4 * s + q;
            float4 bb = *(const float4*)(sB14 + 4 * k);
            float ai = bb.x, af = bb.y, ag = bb.z, ao = bb.w;
            dot4x32(sWih1, q * 32, s, h0, ai, af, ag, ao);  // input part
            dot4x32(sWhh1, q * 32, s, h1, ai, af, ag, ao);  // recurrent part
            float gi = sigm(ai), gf = sigm(af);
            float gg = tanh_fast(ag), go = sigm(ao);
            float cc = fmaf(gf, c1[q], gi * gg);
            c1[q] = cc;
            hn[q] = go * tanh_fast(cc);
        }
#pragma unroll
        for (int b = 0; b < 8; ++b)
#pragma unroll
            for (int q = 0; q < 4; ++q)
                h1[4 * b + q] = __int_as_float(
                    __builtin_amdgcn_ds_bpermute(sel[b], __float_as_int(hn[q])));
    }

    // ---------- fc head: lane s computes columns 2s, 2s+1 ----------
    float acc = 0.f;
#pragma unroll
    for (int mm = 0; mm < 2; ++mm) {
        int m = 2 * s + mm;
        float y = sBfc1[m];
#pragma unroll
        for (int j = 0; j < 32; ++j)
            y = fmaf(h1[j], sFc1[j * 16 + m], y);
        acc = fmaf(fmaxf(y, 0.f), sWfc2[m], acc);
    }
#pragma unroll
    for (int off = 1; off < 8; off <<= 1)
        acc += __shfl_xor(acc, off, 8);
    if (s == 0) out[node] = acc + sBfc2;
}

extern "C" void kernel_launch(void* const* d_in, const int* in_sizes, int n_in,
                              void* d_out, int out_size, void* d_ws, size_t ws_size,
                              hipStream_t stream) {
    (void)in_sizes; (void)n_in; (void)out_size; (void)d_ws; (void)ws_size;
    const float* x    = (const float*)d_in[0];
    // d_in[1] edge_index and d_in[2..9] (GCN weights) are dead code in the reference
    const float* Wtp  = (const float*)d_in[10];
    const float* btp  = (const float*)d_in[11];
    const float* Wih0 = (const float*)d_in[12];
    const float* Whh0 = (const float*)d_in[13];
    const float* bih0 = (const float*)d_in[14];
    const float* bhh0 = (const float*)d_in[15];
    const float* Wih1 = (const float*)d_in[16];
    const float* Whh1 = (const float*)d_in[17];
    const float* bih1 = (const float*)d_in[18];
    const float* bhh1 = (const float*)d_in[19];
    const float* Wfc1 = (const float*)d_in[20];
    const float* bfc1 = (const float*)d_in[21];
    const float* Wfc2 = (const float*)d_in[22];
    const float* bfc2 = (const float*)d_in[23];
    float* out = (float*)d_out;

    dim3 grid((NN + 63) / 64), block(512);
    hipLaunchKernelGGL(lstm_fused, grid, block, 0, stream,
                       x, Wtp, btp, Wih0, Whh0, bih0, bhh0,
                       Wih1, Whh1, bih1, bhh1, Wfc1, bfc1, Wfc2, bfc2, out);
}

// Round 2
// 12865.417 us; speedup vs baseline: 1.0004x; 1.0004x over previous
//
#include <hip/hip_runtime.h>
#include <hip/hip_bf16.h>

#define NN     100000
#define SEQ    12
#define WSTR   36   // padded LDS row stride (floats): 144 B, 16B-aligned, banks 4s apart

__device__ __forceinline__ float rcp_fast(float v) { return __builtin_amdgcn_rcpf(v); }
__device__ __forceinline__ float sigm(float v) { return rcp_fast(1.0f + __expf(-v)); }
__device__ __forceinline__ float tanh_fast(float v) {
    return fmaf(-2.0f, rcp_fast(1.0f + __expf(2.0f * v)), 1.0f);
}

// Accumulate 4 gate-row dot products (i,f,g,o) over a 32-vector h.
// Rows for (q, sublane s) are stored at permuted LDS rows rowbase + {0,8,16,24} + s.
__device__ __forceinline__ void dot4x32(const float* w, int rowbase, int s,
                                        const float (&h)[32],
                                        float& ai, float& af, float& ag, float& ao)
{
    const float4* pi = (const float4*)(w + (rowbase +  0 + s) * WSTR);
    const float4* pf = (const float4*)(w + (rowbase +  8 + s) * WSTR);
    const float4* pg = (const float4*)(w + (rowbase + 16 + s) * WSTR);
    const float4* po = (const float4*)(w + (rowbase + 24 + s) * WSTR);
#pragma unroll
    for (int j4 = 0; j4 < 8; ++j4) {
        float4 wa = pi[j4], wb = pf[j4], wc = pg[j4], wd = po[j4];
        ai = fmaf(wa.x, h[4*j4+0], ai); ai = fmaf(wa.y, h[4*j4+1], ai);
        ai = fmaf(wa.z, h[4*j4+2], ai); ai = fmaf(wa.w, h[4*j4+3], ai);
        af = fmaf(wb.x, h[4*j4+0], af); af = fmaf(wb.y, h[4*j4+1], af);
        af = fmaf(wb.z, h[4*j4+2], af); af = fmaf(wb.w, h[4*j4+3], af);
        ag = fmaf(wc.x, h[4*j4+0], ag); ag = fmaf(wc.y, h[4*j4+1], ag);
        ag = fmaf(wc.z, h[4*j4+2], ag); ag = fmaf(wc.w, h[4*j4+3], ag);
        ao = fmaf(wd.x, h[4*j4+0], ao); ao = fmaf(wd.y, h[4*j4+1], ao);
        ao = fmaf(wd.z, h[4*j4+2], ao); ao = fmaf(wd.w, h[4*j4+3], ao);
    }
}

// 8 lanes per node; sublane s owns hidden units k = 4s+q, q in [0,4).
// Weight row r = 32*T + k  ->  permuted LDS row rho(r) = (r&3)*32 + (r>>2) = q*32 + 8T + s.
// __launch_bounds__(512, 2): 2 waves/EU floor -> 256-VGPR budget. With the default
// budget (128) the compiler spilled h0[32]/h1[32] to scratch -> 32 GB HBM traffic.
__global__ __launch_bounds__(512, 2)
void lstm_fused(const float* __restrict__ x,
                const float* __restrict__ Wtp,  const float* __restrict__ btp,
                const float* __restrict__ Wih0, const float* __restrict__ Whh0,
                const float* __restrict__ bih0, const float* __restrict__ bhh0,
                const float* __restrict__ Wih1, const float* __restrict__ Whh1,
                const float* __restrict__ bih1, const float* __restrict__ bhh1,
                const float* __restrict__ Wfc1, const float* __restrict__ bfc1,
                const float* __restrict__ Wfc2, const float* __restrict__ bfc2,
                float* __restrict__ out)
{
    __shared__ __align__(16) float sWhh0[128 * WSTR];
    __shared__ __align__(16) float sWih1[128 * WSTR];
    __shared__ __align__(16) float sWhh1[128 * WSTR];
    __shared__ __align__(16) float sU4[128];   // [k*4 + T]: folded layer0 input weight
    __shared__ __align__(16) float sV4[128];   // [k*4 + T]: folded layer0 bias
    __shared__ __align__(16) float sB14[128];  // [k*4 + T]: bih1 + bhh1
    __shared__ __align__(16) float sFc1[512];  // W_fc1 [32][16] row-major
    __shared__ float sBfc1[16], sWfc2[16], sBfc2;

    const int tid = threadIdx.x;

    // ---- stage weights into LDS (permuted rows, padded stride) ----
#pragma unroll
    for (int it = 0; it < 8; ++it) {
        int i = tid + it * 512;
        int r = i >> 5, j = i & 31;
        int rho = (r & 3) * 32 + (r >> 2);
        sWhh0[rho * WSTR + j] = Whh0[i];
        sWih1[rho * WSTR + j] = Wih1[i];
        sWhh1[rho * WSTR + j] = Whh1[i];
    }
    if (tid < 128) {
        // fold temporal_proj into layer-0 input projection:
        // pre0[row] = x_t * u[row] + v[row]
        float uu = 0.f, vv = 0.f;
#pragma unroll
        for (int d = 0; d < 16; ++d) {
            float w = Wih0[tid * 16 + d];
            uu = fmaf(w, Wtp[d], uu);
            vv = fmaf(w, btp[d], vv);
        }
        int k = tid & 31, T = tid >> 5;
        sU4[k * 4 + T]  = uu;
        sV4[k * 4 + T]  = vv + bih0[tid] + bhh0[tid];
        sB14[k * 4 + T] = bih1[tid] + bhh1[tid];
    }
    sFc1[tid] = Wfc1[tid];  // exactly 512 elements
    if (tid < 16) { sBfc1[tid] = bfc1[tid]; sWfc2[tid] = Wfc2[tid]; }
    if (tid == 0) sBfc2 = bfc2[0];
    __syncthreads();

    const int s    = tid & 7;
    const int node = blockIdx.x * 64 + (tid >> 3);
    if (node >= NN) return;   // whole waves only (64 thr = 8 nodes, boundary aligned)

    const int lane = tid & 63;
    int sel[8];
#pragma unroll
    for (int b = 0; b < 8; ++b) sel[b] = ((lane & ~7) + b) << 2;

    float h0[32], h1[32], c0[4], c1[4], hn[4];
#pragma unroll
    for (int j = 0; j < 32; ++j) { h0[j] = 0.f; h1[j] = 0.f; }
#pragma unroll
    for (int q = 0; q < 4; ++q) { c0[q] = 0.f; c1[q] = 0.f; }

    const float* xp = x + node * 32 + 20;   // last 12 features

#pragma unroll 1
    for (int t = 0; t < SEQ; ++t) {
        float xt = xp[t];

        // ---------- layer 0 ----------
#pragma unroll
        for (int q = 0; q < 4; ++q) {
            int k = 4 * s + q;
            float4 u = *(const float4*)(sU4 + 4 * k);
            float4 v = *(const float4*)(sV4 + 4 * k);
            float ai = fmaf(xt, u.x, v.x);
            float af = fmaf(xt, u.y, v.y);
            float ag = fmaf(xt, u.z, v.z);
            float ao = fmaf(xt, u.w, v.w);
            dot4x32(sWhh0, q * 32, s, h0, ai, af, ag, ao);
            float gi = sigm(ai), gf = sigm(af);
            float gg = tanh_fast(ag), go = sigm(ao);
            float cc = fmaf(gf, c0[q], gi * gg);
            c0[q] = cc;
            hn[q] = go * tanh_fast(cc);
        }
        // replicate new h0 to all 8 lanes of the node
#pragma unroll
        for (int b = 0; b < 8; ++b)
#pragma unroll
            for (int q = 0; q < 4; ++q)
                h0[4 * b + q] = __int_as_float(
                    __builtin_amdgcn_ds_bpermute(sel[b], __float_as_int(hn[q])));

        // ---------- layer 1 ----------
#pragma unroll
        for (int q = 0; q < 4; ++q) {
            int k = 4 * s + q;
            float4 bb = *(const float4*)(sB14 + 4 * k);
            float ai = bb.x, af = bb.y, ag = bb.z, ao = bb.w;
            dot4x32(sWih1, q * 32, s, h0, ai, af, ag, ao);  // input part
            dot4x32(sWhh1, q * 32, s, h1, ai, af, ag, ao);  // recurrent part
            float gi = sigm(ai), gf = sigm(af);
            float gg = tanh_fast(ag), go = sigm(ao);
            float cc = fmaf(gf, c1[q], gi * gg);
            c1[q] = cc;
            hn[q] = go * tanh_fast(cc);
        }
#pragma unroll
        for (int b = 0; b < 8; ++b)
#pragma unroll
            for (int q = 0; q < 4; ++q)
                h1[4 * b + q] = __int_as_float(
                    __builtin_amdgcn_ds_bpermute(sel[b], __float_as_int(hn[q])));
    }

    // ---------- fc head: lane s computes columns 2s, 2s+1 ----------
    float acc = 0.f;
#pragma unroll
    for (int mm = 0; mm < 2; ++mm) {
        int m = 2 * s + mm;
        float y = sBfc1[m];
#pragma unroll
        for (int j = 0; j < 32; ++j)
            y = fmaf(h1[j], sFc1[j * 16 + m], y);
        acc = fmaf(fmaxf(y, 0.f), sWfc2[m], acc);
    }
#pragma unroll
    for (int off = 1; off < 8; off <<= 1)
        acc += __shfl_xor(acc, off, 8);
    if (s == 0) out[node] = acc + sBfc2;
}

extern "C" void kernel_launch(void* const* d_in, const int* in_sizes, int n_in,
                              void* d_out, int out_size, void* d_ws, size_t ws_size,
                              hipStream_t stream) {
    (void)in_sizes; (void)n_in; (void)out_size; (void)d_ws; (void)ws_size;
    const float* x    = (const float*)d_in[0];
    // d_in[1] edge_index and d_in[2..9] (GCN weights) are dead code in the reference
    const float* Wtp  = (const float*)d_in[10];
    const float* btp  = (const float*)d_in[11];
    const float* Wih0 = (const float*)d_in[12];
    const float* Whh0 = (const float*)d_in[13];
    const float* bih0 = (const float*)d_in[14];
    const float* bhh0 = (const float*)d_in[15];
    const float* Wih1 = (const float*)d_in[16];
    const float* Whh1 = (const float*)d_in[17];
    const float* bih1 = (const float*)d_in[18];
    const float* bhh1 = (const float*)d_in[19];
    const float* Wfc1 = (const float*)d_in[20];
    const float* bfc1 = (const float*)d_in[21];
    const float* Wfc2 = (const float*)d_in[22];
    const float* bfc2 = (const float*)d_in[23];
    float* out = (float*)d_out;

    dim3 grid((NN + 63) / 64), block(512);
    hipLaunchKernelGGL(lstm_fused, grid, block, 0, stream,
                       x, Wtp, btp, Wih0, Whh0, bih0, bhh0,
                       Wih1, Whh1, bih1, bhh1, Wfc1, bfc1, Wfc2, bfc2, out);
}

// Round 3
// 1099.284 us; speedup vs baseline: 11.7076x; 11.7034x over previous
//
#include <hip/hip_runtime.h>

#define NN  100000
#define SEQ 12

// d_ws float offsets (repacked weights)
#define OFF_UV   0        // [32][8]: k*8 + {u_i,u_f,u_g,u_o, v_i,v_f,v_g,v_o}
#define OFF_W0   256      // [32][4][32]  Whh0 rows grouped per unit k
#define OFF_W1   4352     // [32][4][64]  [Wih1 | Whh1] rows grouped per unit k
#define OFF_B1   12544    // [32][4]      bih1+bhh1
#define OFF_FC1  12672    // [16][32]     W_fc1 transposed
#define OFF_BFC1 13184    // [16]
#define OFF_FC2  13200    // [16]
#define OFF_BFC2 13216    // [1]

__device__ __forceinline__ float rcp_fast(float v) { return __builtin_amdgcn_rcpf(v); }
__device__ __forceinline__ float sigm(float v) { return rcp_fast(1.0f + __expf(-v)); }
__device__ __forceinline__ float tanh_fast(float v) {
    return fmaf(-2.0f, rcp_fast(1.0f + __expf(2.0f * v)), 1.0f);
}

// One-block repack: fold temporal_proj into layer-0 input projection, regroup
// all LSTM weights unit-major so the main kernel streams them with uniform
// (scalar) loads, pre-sum biases, transpose fc1.
__global__ void repack(const float* __restrict__ Wtp,  const float* __restrict__ btp,
                       const float* __restrict__ Wih0, const float* __restrict__ Whh0,
                       const float* __restrict__ bih0, const float* __restrict__ bhh0,
                       const float* __restrict__ Wih1, const float* __restrict__ Whh1,
                       const float* __restrict__ bih1, const float* __restrict__ bhh1,
                       const float* __restrict__ Wfc1, const float* __restrict__ bfc1,
                       const float* __restrict__ Wfc2, const float* __restrict__ bfc2,
                       float* __restrict__ ws)
{
    const int tid = threadIdx.x;  // 256 threads
    if (tid < 128) {
        int k = tid >> 2, g = tid & 3;
        int r = g * 32 + k;                 // PyTorch gate-major row (i,f,g,o)
        float u = 0.f, v = 0.f;
        for (int d = 0; d < 16; ++d) {
            u = fmaf(Wih0[r * 16 + d], Wtp[d], u);
            v = fmaf(Wih0[r * 16 + d], btp[d], v);
        }
        ws[OFF_UV + k * 8 + g]     = u;
        ws[OFF_UV + k * 8 + 4 + g] = v + bih0[r] + bhh0[r];
        ws[OFF_B1 + tid]           = bih1[r] + bhh1[r];   // [k*4+g]
    }
    for (int idx = tid; idx < 4096; idx += 256) {
        int k = idx >> 7, rem = idx & 127, g = rem >> 5, j = rem & 31;
        ws[OFF_W0 + idx] = Whh0[(g * 32 + k) * 32 + j];
    }
    for (int idx = tid; idx < 8192; idx += 256) {
        int k = idx >> 8, rem = idx & 255, g = rem >> 6, j = rem & 63;
        ws[OFF_W1 + idx] = (j < 32) ? Wih1[(g * 32 + k) * 32 + j]
                                    : Whh1[(g * 32 + k) * 32 + j - 32];
    }
    for (int idx = tid; idx < 512; idx += 256) {
        int m = idx >> 5, j = idx & 31;
        ws[OFF_FC1 + idx] = Wfc1[j * 16 + m];
    }
    if (tid < 16) { ws[OFF_BFC1 + tid] = bfc1[tid]; ws[OFF_FC2 + tid] = Wfc2[tid]; }
    if (tid == 0) ws[OFF_BFC2] = bfc2[0];
}

// One node per lane. All weight accesses are wave-uniform -> s_load (SGPR
// broadcast): zero LDS, each scalar weight feeds 64 lanes' FMAs. Node state
// (h0,h1,c0,c1 = 128 f32) lives in VGPRs; amdgpu_waves_per_eu(2,2) caps the
// occupancy target at 2 waves/EU so the allocator gets a 256-VGPR budget
// (launch_bounds min-waves alone did NOT raise it — R2 evidence).
__global__ __launch_bounds__(256) __attribute__((amdgpu_waves_per_eu(2, 2)))
void lstm_main(const float* __restrict__ x, const float* __restrict__ ws,
               float* __restrict__ out)
{
    const int node = blockIdx.x * 256 + threadIdx.x;
    if (node >= NN) return;

    float xv[SEQ];
#pragma unroll
    for (int t = 0; t < SEQ; ++t) xv[t] = x[node * 32 + 20 + t];

    float h0[32], h1[32], c0[32], c1[32], hn[32];
#pragma unroll
    for (int j = 0; j < 32; ++j) { h0[j] = 0.f; h1[j] = 0.f; c0[j] = 0.f; c1[j] = 0.f; }

#pragma unroll 1
    for (int t = 0; t < SEQ; ++t) {
        const float xt = xv[t];

        // ---------------- layer 0 ----------------
#pragma unroll
        for (int k = 0; k < 32; ++k) {
            const float* uv = ws + OFF_UV + k * 8;
            const float* wp = ws + OFF_W0 + k * 128;
            float ai = fmaf(xt, uv[0], uv[4]);
            float af = fmaf(xt, uv[1], uv[5]);
            float ag = fmaf(xt, uv[2], uv[6]);
            float ao = fmaf(xt, uv[3], uv[7]);
#pragma unroll
            for (int j = 0; j < 32; ++j) {
                const float hj = h0[j];
                ai = fmaf(wp[j],      hj, ai);
                af = fmaf(wp[32 + j], hj, af);
                ag = fmaf(wp[64 + j], hj, ag);
                ao = fmaf(wp[96 + j], hj, ao);
            }
            const float gi = sigm(ai), gf = sigm(af);
            const float gg = tanh_fast(ag), go = sigm(ao);
            const float cc = fmaf(gf, c0[k], gi * gg);
            c0[k] = cc;
            hn[k] = go * tanh_fast(cc);
        }
#pragma unroll
        for (int j = 0; j < 32; ++j) h0[j] = hn[j];

        // ---------------- layer 1 ----------------
#pragma unroll
        for (int k = 0; k < 32; ++k) {
            const float* wp = ws + OFF_W1 + k * 256;   // [g][64]: j<32 -> h0, j>=32 -> h1
            const float* bp = ws + OFF_B1 + k * 4;
            float ai = bp[0], af = bp[1], ag = bp[2], ao = bp[3];
#pragma unroll
            for (int j = 0; j < 32; ++j) {
                const float hj = h0[j];
                ai = fmaf(wp[j],       hj, ai);
                af = fmaf(wp[64 + j],  hj, af);
                ag = fmaf(wp[128 + j], hj, ag);
                ao = fmaf(wp[192 + j], hj, ao);
            }
#pragma unroll
            for (int j = 0; j < 32; ++j) {
                const float hj = h1[j];
                ai = fmaf(wp[32 + j],  hj, ai);
                af = fmaf(wp[96 + j],  hj, af);
                ag = fmaf(wp[160 + j], hj, ag);
                ao = fmaf(wp[224 + j], hj, ao);
            }
            const float gi = sigm(ai), gf = sigm(af);
            const float gg = tanh_fast(ag), go = sigm(ao);
            const float cc = fmaf(gf, c1[k], gi * gg);
            c1[k] = cc;
            hn[k] = go * tanh_fast(cc);
        }
#pragma unroll
        for (int j = 0; j < 32; ++j) h1[j] = hn[j];
    }

    // ---------------- fc head ----------------
    float acc = ws[OFF_BFC2];
#pragma unroll
    for (int m = 0; m < 16; ++m) {
        const float* fp = ws + OFF_FC1 + m * 32;
        float y = ws[OFF_BFC1 + m];
#pragma unroll
        for (int j = 0; j < 32; ++j) y = fmaf(fp[j], h1[j], y);
        acc = fmaf(fmaxf(y, 0.f), ws[OFF_FC2 + m], acc);
    }
    out[node] = acc;
}

extern "C" void kernel_launch(void* const* d_in, const int* in_sizes, int n_in,
                              void* d_out, int out_size, void* d_ws, size_t ws_size,
                              hipStream_t stream) {
    (void)in_sizes; (void)n_in; (void)out_size; (void)ws_size;
    const float* x    = (const float*)d_in[0];
    // d_in[1] edge_index and d_in[2..9] (GCN weights) are dead code in the reference
    const float* Wtp  = (const float*)d_in[10];
    const float* btp  = (const float*)d_in[11];
    const float* Wih0 = (const float*)d_in[12];
    const float* Whh0 = (const float*)d_in[13];
    const float* bih0 = (const float*)d_in[14];
    const float* bhh0 = (const float*)d_in[15];
    const float* Wih1 = (const float*)d_in[16];
    const float* Whh1 = (const float*)d_in[17];
    const float* bih1 = (const float*)d_in[18];
    const float* bhh1 = (const float*)d_in[19];
    const float* Wfc1 = (const float*)d_in[20];
    const float* bfc1 = (const float*)d_in[21];
    const float* Wfc2 = (const float*)d_in[22];
    const float* bfc2 = (const float*)d_in[23];
    float* ws  = (float*)d_ws;
    float* out = (float*)d_out;

    hipLaunchKernelGGL(repack, dim3(1), dim3(256), 0, stream,
                       Wtp, btp, Wih0, Whh0, bih0, bhh0,
                       Wih1, Whh1, bih1, bhh1, Wfc1, bfc1, Wfc2, bfc2, ws);
    hipLaunchKernelGGL(lstm_main, dim3((NN + 255) / 256), dim3(256), 0, stream,
                       x, ws, out);
}